// Round 4
// baseline (154.343 us; speedup 1.0000x reference)
//
#include <hip/hip_runtime.h>
#include <hip/hip_bf16.h>

// KAN linear == GEMM M=8192, N=512, K=4096 (8 Chebyshev/silu feats per input,
// basis_0 folded into bias). A generated in-register -> LDS; W prepped once (4 MB bf16).
// BM=32 x BN=256: grid 512 (2 blocks/CU), A-gen redundancy only 2x.
#define IN_FEAT 512
#define OUT_FEAT 512
#define NTOK 8192
#define KDIM 4096

#define BM 32
#define BN 256
#define BK 64          // 8 inputs x 8 basis feats per K-iter

typedef short bf16x8 __attribute__((ext_vector_type(8)));
typedef float f32x4 __attribute__((ext_vector_type(4)));

static __device__ inline short f2bf(float f) {
    union { float f; unsigned u; } v; v.f = f;
    unsigned u = v.u;
    u += 0x7fffu + ((u >> 16) & 1u);   // RNE
    return (short)(u >> 16);
}

// pack two fp32 -> bf16 pair (round-half-up): 2 adds + v_perm
static __device__ inline unsigned pack2bf(float f0, float f1) {
    union { float f; unsigned u; } a, b; a.f = f0; b.f = f1;
    return __builtin_amdgcn_perm(b.u + 0x8000u, a.u + 0x8000u, 0x07060302u);
}

static __device__ inline void gload_lds16(const short* g, short* l) {
    __builtin_amdgcn_global_load_lds(
        (const __attribute__((address_space(1))) unsigned int*)g,
        (__attribute__((address_space(3))) unsigned int*)l,
        16, 0, 0);
}

// ---------------- prep: W bf16 [512 x 4096] + folded bias ----------------
__global__ __launch_bounds__(256) void kan_prep(
    const float* __restrict__ coeff, const float* __restrict__ scale_base,
    const float* __restrict__ scale_spline, const float* __restrict__ base_bias,
    short* __restrict__ Wb, float* __restrict__ bias)
{
    int o = blockIdx.x;
    int tid = threadIdx.x;
    float local = 0.f;
#pragma unroll
    for (int rep = 0; rep < 2; ++rep) {
        int i = tid + rep * 256;
        size_t oi = (size_t)o * IN_FEAT + i;
        const float4* c4 = (const float4*)(coeff + oi * 8);
        float4 ca = c4[0], cb = c4[1];
        float ss = scale_spline[oi];
        float sb = scale_base[oi];
        local += base_bias[oi] + ss * ca.x;
        bf16x8 w;
        w[0] = f2bf(sb);
        w[1] = f2bf(ss * ca.y); w[2] = f2bf(ss * ca.z); w[3] = f2bf(ss * ca.w);
        w[4] = f2bf(ss * cb.x); w[5] = f2bf(ss * cb.y); w[6] = f2bf(ss * cb.z);
        w[7] = f2bf(ss * cb.w);
        *(bf16x8*)(Wb + (size_t)o * KDIM + (size_t)i * 8) = w;
    }
    __shared__ float red[4];
    for (int off = 32; off > 0; off >>= 1) local += __shfl_down(local, off, 64);
    int lane = tid & 63, wv = tid >> 6;
    if (lane == 0) red[wv] = local;
    __syncthreads();
    if (tid == 0) bias[o] = red[0] + red[1] + red[2] + red[3];
}

// ---------------- fused GEMM: BM=32 x BN=256, dbuf LDS, 1 barrier/iter ----------------
// LDS layout (A and B): row r, logical 16B chunk c stored at phys chunk c^(r&7).
__global__ __launch_bounds__(256, 2) void kan_gemm4(
    const float* __restrict__ x, const short* __restrict__ Wb,
    const float* __restrict__ bias, float* __restrict__ out)
{
    __shared__ __align__(16) short As[2][BM * BK];   // 2 x 4 KB
    __shared__ __align__(16) short Bs[2][BN * BK];   // 2 x 32 KB

    int tid = threadIdx.x;
    int nb = blockIdx.x & 1;         // nb fastest -> x rows shared across nb hit L2
    int mb = blockIdx.x >> 1;
    int m0 = mb * BM, o0 = nb * BN;

    int lane = tid & 63, wv = tid >> 6;
    int qd = lane >> 4, ln15 = lane & 15;

    f32x4 acc[2][4];
#pragma unroll
    for (int a = 0; a < 2; ++a)
#pragma unroll
        for (int b = 0; b < 4; ++b) acc[a][b] = (f32x4)0.f;

    // ---- A-gen: one input-chunk per thread per iter ----
    int tok = tid >> 3;              // 0..31
    int inp = tid & 7;               // which of the 8 inputs in this K-iter
    const float* xq = x + (size_t)(m0 + tok) * IN_FEAT + inp;
    int aoff = tok * BK + (inp ^ (tok & 7)) * 8;   // swizzled LDS chunk (shorts)

    // ---- B DMA: wave wv stages rows [wv*64, wv*64+64) in 8 calls of 8 rows ----
    int rg = lane >> 3;              // row-in-group 0..7
    int c_log = (lane & 7) ^ rg;     // fetch logical chunk so phys (lane&7) is swizzled
    const short* Bg = Wb + (size_t)(o0 + wv * 64 + rg) * KDIM + c_log * 8;

#define GEN_CHUNK(xval, buf)                                                  \
    {                                                                         \
        float xc = fminf(fmaxf((xval), -1.f), 1.f);                           \
        float bse = xc / (1.f + __expf(-xc));                                 \
        float b2 = 2.f * xc * xc - 1.f;                                       \
        float b3 = 2.f * xc * b2 - 1.f;                                       \
        float b4 = 2.f * xc * b3 - 1.f;                                       \
        float b5 = 2.f * xc * b4 - 1.f;                                       \
        float b6 = 2.f * xc * b5 - 1.f;                                       \
        float b7 = 2.f * xc * b6 - 1.f;                                       \
        uint4 pk;                                                             \
        pk.x = pack2bf(bse, xc); pk.y = pack2bf(b2, b3);                      \
        pk.z = pack2bf(b4, b5);  pk.w = pack2bf(b6, b7);                      \
        *(uint4*)&As[buf][aoff] = pk;                                         \
    }

    // ---- prologue: stage iter 0 ----
    {
#pragma unroll
        for (int j = 0; j < 8; ++j)
            gload_lds16(Bg + (size_t)j * 8 * KDIM, &Bs[0][(wv * 64 + j * 8) * BK]);
        float xv = xq[0];
        GEN_CHUNK(xv, 0);
    }

    int cur = 0;
    for (int it = 0; it < IN_FEAT / 8; ++it, cur ^= 1) {
        __syncthreads();             // buf[cur] ready (DMA+ds_writes drained); buf[nxt] free
        if (it < IN_FEAT / 8 - 1) {
            int nxt = cur ^ 1;
            const short* bsrc = Bg + (it + 1) * BK;
#pragma unroll
            for (int j = 0; j < 8; ++j)
                gload_lds16(bsrc + (size_t)j * 8 * KDIM, &Bs[nxt][(wv * 64 + j * 8) * BK]);
            float xv = xq[(it + 1) * 8];
            GEN_CHUNK(xv, nxt);
        }
        // ---- MFMA on buf[cur]: wave tile 32m x 64n ----
#pragma unroll
        for (int kq = 0; kq < 2; ++kq) {
            bf16x8 af[2], bfv[4];
#pragma unroll
            for (int fm = 0; fm < 2; ++fm) {
                int row = fm * 16 + ln15;
                af[fm] = *(const bf16x8*)&As[cur][row * BK + ((kq * 4 + qd) ^ (row & 7)) * 8];
            }
#pragma unroll
            for (int fn = 0; fn < 4; ++fn) {
                int row = wv * 64 + fn * 16 + ln15;
                bfv[fn] = *(const bf16x8*)&Bs[cur][row * BK + ((kq * 4 + qd) ^ (row & 7)) * 8];
            }
#pragma unroll
            for (int fm = 0; fm < 2; ++fm)
#pragma unroll
                for (int fn = 0; fn < 4; ++fn)
                    acc[fm][fn] = __builtin_amdgcn_mfma_f32_16x16x32_bf16(
                        af[fm], bfv[fn], acc[fm][fn], 0, 0, 0);
        }
    }
#undef GEN_CHUNK

    // ---- epilogue: C/D row = qd*4+reg, col = ln15 ----
#pragma unroll
    for (int fn = 0; fn < 4; ++fn) {
        int o = o0 + wv * 64 + fn * 16 + ln15;
        float bv = bias[o];
#pragma unroll
        for (int fm = 0; fm < 2; ++fm) {
            int r0 = m0 + fm * 16 + qd * 4;
#pragma unroll
            for (int r = 0; r < 4; ++r)
                out[(size_t)(r0 + r) * OUT_FEAT + o] = acc[fm][fn][r] + bv;
        }
    }
}

extern "C" void kernel_launch(void* const* d_in, const int* in_sizes, int n_in,
                              void* d_out, int out_size, void* d_ws, size_t ws_size,
                              hipStream_t stream) {
    const float* x            = (const float*)d_in[0];
    const float* coeff        = (const float*)d_in[1];
    const float* scale_base   = (const float*)d_in[2];
    const float* scale_spline = (const float*)d_in[3];
    const float* base_bias    = (const float*)d_in[4];
    float* out = (float*)d_out;

    short* Wb   = (short*)d_ws;                                  // 4 MB
    float* bias = (float*)((char*)d_ws + (size_t)OUT_FEAT * KDIM * 2);

    kan_prep<<<OUT_FEAT, 256, 0, stream>>>(coeff, scale_base, scale_spline, base_bias, Wb, bias);
    kan_gemm4<<<(NTOK / BM) * (OUT_FEAT / BN), 256, 0, stream>>>(x, Wb, bias, out);
}